// Round 4
// baseline (389.614 us; speedup 1.0000x reference)
//
#include <hip/hip_runtime.h>
#include <stdint.h>

#define HW   1369      // 37*37 output pixels
#define QW   39        // padded row width
#define QP   1616      // padded plane rows per (b) in Xp
#define QT   1536      // q rows in x1 (per batch)
#define CIN  1024
#define CMID 512
#define KTOT 9216      // 9 * 1024
#define NTIL 144       // K-tiles: 9 taps * 16 cblocks of 64

typedef float  f32x4  __attribute__((ext_vector_type(4)));
typedef __bf16 bf16x8 __attribute__((ext_vector_type(8)));

__device__ __forceinline__ uint16_t f2bf(float f) {
  uint32_t u = __float_as_uint(f);
  u += 0x7fffu + ((u >> 16) & 1u);
  return (uint16_t)(u >> 16);
}

// global -> LDS direct copy, 16B per lane. LDS dest = wave-uniform base + lane*16.
__device__ __forceinline__ void gll16(const void* g, void* l) {
  const __attribute__((address_space(1))) uint32_t* ga =
      (const __attribute__((address_space(1))) uint32_t*)(uintptr_t)g;
  __attribute__((address_space(3))) uint32_t* la =
      (__attribute__((address_space(3))) uint32_t*)(uint32_t)(uintptr_t)l;
  __builtin_amdgcn_global_load_lds(ga, la, 16, 0, 0);
}

// ---------- prep: fmap [b][c][h][w] f32 -> Xp [b][q][c] bf16 (padded, zeroed border) ----------
__global__ void k_pad_transpose(const float* __restrict__ fmap, uint16_t* __restrict__ Xp) {
  __shared__ float t[32][33];
  const int b = blockIdx.z;
  const int c0 = blockIdx.y * 32;
  const int p0 = blockIdx.x * 32;
  const int tx = threadIdx.x, ty = threadIdx.y;
  const float* src = fmap + ((size_t)b * CIN + c0) * HW + p0;
#pragma unroll
  for (int i = 0; i < 4; ++i) {
    int cc = ty + i * 8;
    t[cc][tx] = (p0 + tx < HW) ? src[(size_t)cc * HW + tx] : 0.f;
  }
  __syncthreads();
#pragma unroll
  for (int i = 0; i < 4; ++i) {
    int pl = ty + i * 8;
    int p = p0 + pl;
    if (p < HW) {
      int h = p / 37, w = p - h * 37;
      int q = (h + 1) * QW + (w + 1);
      Xp[((size_t)b * QP + q) * CIN + c0 + tx] = f2bf(t[tx][pl]);
    }
  }
}

// ---------- prep: W1 [o][c][3][3] f32 -> Apk [o][r*1024+c] bf16 ----------
__global__ void k_pack_w1(const float* __restrict__ W1, uint16_t* __restrict__ Apk) {
  int idx = blockIdx.x * 256 + threadIdx.x;
  if (idx >= 512 * KTOT) return;
  int o = idx / KTOT, k = idx - o * KTOT;
  int r = k >> 10, c = k & 1023;
  Apk[idx] = f2bf(W1[((size_t)o * CIN + c) * 9 + r]);
}

// ---------- prep: W2 [120][512] f32 -> W2p [128][512] bf16 ----------
__global__ void k_pack_w2(const float* __restrict__ W2, uint16_t* __restrict__ W2p) {
  int idx = blockIdx.x * 256 + threadIdx.x;
  int j = idx >> 9, o = idx & 511;
  W2p[idx] = (j < 120) ? f2bf(W2[j * 512 + o]) : (uint16_t)0;
}

// ---------- conv1: deep-pipelined implicit GEMM ----------
// BM=256(q) x BN=128(o) x BK=64, 4 waves (2Mx2N, per-wave 128x64), 3 LDS slots.
// Slot = A[256][64] (32KB) + B[128][64] (16KB) = 48KB; 3 slots = 144KB.
// T2: byte ^= (row&7)<<4 swizzle (pre-swizzled global src, swizzled ds_read).
// T3/T4: 4 phases/tile, stage tile t+2 (3 loads/phase), counted vmcnt(12).
// T5: setprio around each 16-MFMA cluster.
__global__ __launch_bounds__(256, 1) void k_conv1(
    const uint16_t* __restrict__ Xp, const uint16_t* __restrict__ Apk,
    const float* __restrict__ b1, uint16_t* __restrict__ x1) {
  __shared__ __align__(16) uint16_t lds[3 * 24576];   // 147456 B

  const int tid  = threadIdx.x;
  const int wid  = tid >> 6, lane = tid & 63;
  const int lrow = lane & 15, lq = lane >> 4;
  const int wm   = wid >> 1,  wn = wid & 1;

  // grid decode + XCD chunked swizzle (384 = 8 * 48; nt-major so a chunk shares the B panel)
  const int bid = blockIdx.x;
  const int nb  = (bid & 7) * 48 + (bid >> 3);
  const int nt  = nb / 96, mt = nb - nt * 96;
  const int batch = mt / 6, qb = (mt - batch * 6) * 256;
  const int o0 = nt * 128;
  const uint16_t* Xb = Xp + (size_t)batch * QP * CIN;

  // fragment-read swizzled column offsets (elements).
  // Swizzle permutation on byte bits 4-6: lds_byte = global_byte ^ ((row&7)<<4).
  const int xorb    = (lrow & 7) << 4;
  const int col_el0 = ((lq * 16) ^ xorb) >> 1;   // kk=0
  const int col_el1 = col_el0 ^ 32;              // kk=1: toggle byte bit 6 (XOR, not add!)

  // staging: per-thread pre-swizzled source column (elements) and row-sub
  const int scol = (((tid & 7) ^ ((tid >> 3) & 7)) << 4) >> 1;
  const int srow = tid >> 3;                     // 0..31

  f32x4 acc[8][4] = {};

#define STAGE3(u, j0) do {                                                            \
    if ((u) < NTIL) {                                                                 \
      const int tap_ = (u) >> 4;                                                      \
      const int off_ = (tap_ / 3) * QW + tap_ % 3;                                    \
      const int c0_  = ((u) & 15) << 6;                                               \
      uint16_t* sl = lds + ((u) % 3) * 24576;                                         \
      _Pragma("unroll")                                                               \
      for (int jj = 0; jj < 3; ++jj) {                                                \
        const int j = (j0) + jj;                                                      \
        if (j < 8) {                                                                  \
          const int row = j * 32 + srow;                                              \
          gll16(Xb + (size_t)(qb + off_ + row) * CIN + c0_ + scol,                    \
                sl + j * 2048 + wid * 512);                                           \
        } else {                                                                      \
          const int row = (j - 8) * 32 + srow;                                        \
          gll16(Apk + (size_t)(o0 + row) * KTOT + (tap_ << 10) + c0_ + scol,          \
                sl + j * 2048 + wid * 512);                                           \
        }                                                                             \
      }                                                                               \
    }                                                                                 \
  } while (0)

#define PHASE(rh, kk, stj) do {                                                       \
    bf16x8 av[4], bv[4];                                                              \
    const int ce = (kk) ? col_el1 : col_el0;                                          \
    const uint16_t* As = lds + slot * 24576;                                          \
    const uint16_t* Bs = As + 16384;                                                  \
    _Pragma("unroll")                                                                 \
    for (int m = 0; m < 4; ++m)                                                       \
      av[m] = *(const bf16x8*)(As + (wm * 128 + (rh) * 64 + m * 16 + lrow) * 64 + ce);\
    _Pragma("unroll")                                                                 \
    for (int n = 0; n < 4; ++n)                                                       \
      bv[n] = *(const bf16x8*)(Bs + (wn * 64 + n * 16 + lrow) * 64 + ce);             \
    STAGE3(t + 2, stj);                                                               \
    asm volatile("s_barrier" ::: "memory");                                           \
    __builtin_amdgcn_sched_barrier(0);                                                \
    __builtin_amdgcn_s_setprio(1);                                                    \
    _Pragma("unroll")                                                                 \
    for (int m = 0; m < 4; ++m)                                                       \
      _Pragma("unroll")                                                               \
      for (int n = 0; n < 4; ++n)                                                     \
        acc[(rh) * 4 + m][n] = __builtin_amdgcn_mfma_f32_16x16x32_bf16(               \
            av[m], bv[n], acc[(rh) * 4 + m][n], 0, 0, 0);                             \
    __builtin_amdgcn_s_setprio(0);                                                    \
  } while (0)

  {
    const int t = -2;  // so STAGE3(t+2,..) stages tile 0
    STAGE3(t + 2, 0); STAGE3(t + 2, 3); STAGE3(t + 2, 6); STAGE3(t + 2, 9);
  }
  {
    const int t = -1;  // stages tile 1
    STAGE3(t + 2, 0); STAGE3(t + 2, 3); STAGE3(t + 2, 6); STAGE3(t + 2, 9);
  }

  for (int t = 0; t < NTIL; ++t) {
    const int slot = t % 3;
    if (t == NTIL - 1) asm volatile("s_waitcnt vmcnt(0)" ::: "memory");
    else               asm volatile("s_waitcnt vmcnt(12)" ::: "memory");
    asm volatile("s_barrier" ::: "memory");
    __builtin_amdgcn_sched_barrier(0);
    PHASE(0, 0, 0);
    PHASE(0, 1, 3);
    PHASE(1, 0, 6);
    PHASE(1, 1, 9);
  }

  // epilogue: bias + ReLU6 -> x1 bf16
  const int qr = lq * 4;
#pragma unroll
  for (int n = 0; n < 4; ++n) {
    const int o = o0 + wn * 64 + n * 16 + lrow;
    const float bias = b1[o];
#pragma unroll
    for (int m = 0; m < 8; ++m) {
#pragma unroll
      for (int v = 0; v < 4; ++v) {
        const int q = qb + wm * 128 + m * 16 + qr + v;
        float x = acc[m][n][v] + bias;
        x = fminf(fmaxf(x, 0.f), 6.f);
        x1[((size_t)batch * QT + q) * CMID + o] = f2bf(x);
      }
    }
  }
#undef PHASE
#undef STAGE3
}

// ---------- conv2: out[b][h][w][j] = sum_o x1[q][o] * W2[j][o] + b2[j] ----------
__global__ __launch_bounds__(256, 2) void k_conv2(
    const uint16_t* __restrict__ x1, const uint16_t* __restrict__ W2p,
    const float* __restrict__ b2, float* __restrict__ out) {
  __shared__ __align__(16) uint16_t lA[128 * 64];
  __shared__ __align__(16) uint16_t lB[128 * 64];
  const int tid = threadIdx.x;
  const int wid = tid >> 6, lane = tid & 63;
  const int b = blockIdx.z, q0 = blockIdx.x * 128;
  const uint16_t* Ab = x1 + (size_t)b * QT * CMID;
  const int wm = wid >> 1, wn = wid & 1;
  const int lrow = lane & 15, lk = (lane >> 4) * 8;
  f32x4 acc[4][4] = {};

  for (int kt = 0; kt < 8; ++kt) {
    const int c0 = kt << 6;
#pragma unroll
    for (int i = 0; i < 4; ++i) {
      int wb = i * 256 + wid * 64;
      int chunk = wb + lane;
      int row = chunk >> 3, ch = chunk & 7;
      gll16(Ab + (size_t)(q0 + row) * CMID + c0 + ch * 8, lA + wb * 8);
      gll16(W2p + (size_t)row * CMID + c0 + ch * 8, lB + wb * 8);
    }
    __syncthreads();
#pragma unroll
    for (int kk = 0; kk < 2; ++kk) {
      bf16x8 av[4], bv[4];
#pragma unroll
      for (int mi = 0; mi < 4; ++mi)
        av[mi] = *(const bf16x8*)(lA + (wm * 64 + mi * 16 + lrow) * 64 + kk * 32 + lk);
#pragma unroll
      for (int ni = 0; ni < 4; ++ni)
        bv[ni] = *(const bf16x8*)(lB + (wn * 64 + ni * 16 + lrow) * 64 + kk * 32 + lk);
#pragma unroll
      for (int mi = 0; mi < 4; ++mi)
#pragma unroll
        for (int ni = 0; ni < 4; ++ni)
          acc[mi][ni] = __builtin_amdgcn_mfma_f32_16x16x32_bf16(av[mi], bv[ni], acc[mi][ni], 0, 0, 0);
    }
    __syncthreads();
  }

  const int qr = (lane >> 4) * 4;
#pragma unroll
  for (int ni = 0; ni < 4; ++ni) {
    int j = wn * 64 + ni * 16 + lrow;
    if (j < 120) {
      float bias = b2[j];
#pragma unroll
      for (int mi = 0; mi < 4; ++mi) {
#pragma unroll
        for (int v = 0; v < 4; ++v) {
          int q = q0 + wm * 64 + mi * 16 + qr + v;
          int h = q / QW, w = q - h * QW;
          if (h < 37 && w < 37) {
            out[((size_t)b * HW + h * 37 + w) * 120 + j] = acc[mi][ni][v] + bias;
          }
        }
      }
    }
  }
}

extern "C" void kernel_launch(void* const* d_in, const int* in_sizes, int n_in,
                              void* d_out, int out_size, void* d_ws, size_t ws_size,
                              hipStream_t stream) {
  const float* fmap = (const float*)d_in[0];
  const float* W1   = (const float*)d_in[1];
  const float* b1   = (const float*)d_in[2];
  const float* W2   = (const float*)d_in[3];
  const float* b2   = (const float*)d_in[4];
  float* out = (float*)d_out;

  uint8_t* ws = (uint8_t*)d_ws;
  const size_t XP_BYTES  = (size_t)16 * QP * CIN * 2;   // 52,953,088
  const size_t W1P_BYTES = (size_t)512 * KTOT * 2;      //  9,437,184
  const size_t W2P_BYTES = (size_t)128 * 512 * 2;       //    131,072
  uint16_t* Xp  = (uint16_t*)ws;
  uint16_t* Apk = (uint16_t*)(ws + XP_BYTES);
  uint16_t* W2p = (uint16_t*)(ws + XP_BYTES + W1P_BYTES);
  uint16_t* x1  = (uint16_t*)(ws + XP_BYTES + W1P_BYTES + W2P_BYTES);

  hipMemsetAsync(Xp, 0, XP_BYTES, stream);
  k_pad_transpose<<<dim3(43, 32, 16), dim3(32, 8), 0, stream>>>(fmap, Xp);
  k_pack_w1<<<dim3((512 * KTOT + 255) / 256), dim3(256), 0, stream>>>(W1, Apk);
  k_pack_w2<<<dim3(256), dim3(256), 0, stream>>>(W2, W2p);
  k_conv1<<<dim3(384), dim3(256), 0, stream>>>(Xp, Apk, b1, x1);
  k_conv2<<<dim3(12, 1, 16), dim3(256), 0, stream>>>(x1, W2p, b2, out);
}

// Round 5
// 344.842 us; speedup vs baseline: 1.1298x; 1.1298x over previous
//
#include <hip/hip_runtime.h>
#include <stdint.h>

#define HW   1369      // 37*37 output pixels
#define QW   39        // padded row width
#define QP   1616      // padded plane rows per (b) in Xp
#define QT   1536      // q rows in x1 (per batch)
#define CIN  1024
#define CMID 512
#define KTOT 9216      // 9 * 1024
#define NTIL 144       // K-tiles: 16 cblocks(64) * 9 taps, cblock-major tap-inner

typedef float  f32x4  __attribute__((ext_vector_type(4)));
typedef __bf16 bf16x8 __attribute__((ext_vector_type(8)));

__device__ __forceinline__ uint16_t f2bf(float f) {
  uint32_t u = __float_as_uint(f);
  u += 0x7fffu + ((u >> 16) & 1u);
  return (uint16_t)(u >> 16);
}

// global -> LDS direct copy, 16B per lane. LDS dest = wave-uniform base + lane*16.
__device__ __forceinline__ void gll16(const void* g, void* l) {
  const __attribute__((address_space(1))) uint32_t* ga =
      (const __attribute__((address_space(1))) uint32_t*)(uintptr_t)g;
  __attribute__((address_space(3))) uint32_t* la =
      (__attribute__((address_space(3))) uint32_t*)(uint32_t)(uintptr_t)l;
  __builtin_amdgcn_global_load_lds(ga, la, 16, 0, 0);
}

// ---------- prep: fmap [b][c][h][w] f32 -> Xp [b][q][c] bf16 (padded, zeroed border) ----------
__global__ void k_pad_transpose(const float* __restrict__ fmap, uint16_t* __restrict__ Xp) {
  __shared__ float t[32][33];
  const int b = blockIdx.z;
  const int c0 = blockIdx.y * 32;
  const int p0 = blockIdx.x * 32;
  const int tx = threadIdx.x, ty = threadIdx.y;
  const float* src = fmap + ((size_t)b * CIN + c0) * HW + p0;
#pragma unroll
  for (int i = 0; i < 4; ++i) {
    int cc = ty + i * 8;
    t[cc][tx] = (p0 + tx < HW) ? src[(size_t)cc * HW + tx] : 0.f;
  }
  __syncthreads();
#pragma unroll
  for (int i = 0; i < 4; ++i) {
    int pl = ty + i * 8;
    int p = p0 + pl;
    if (p < HW) {
      int h = p / 37, w = p - h * 37;
      int q = (h + 1) * QW + (w + 1);
      Xp[((size_t)b * QP + q) * CIN + c0 + tx] = f2bf(t[tx][pl]);
    }
  }
}

// ---------- prep: W1 [o][c][3][3] f32 -> Apk [o][r*1024+c] bf16 ----------
__global__ void k_pack_w1(const float* __restrict__ W1, uint16_t* __restrict__ Apk) {
  int idx = blockIdx.x * 256 + threadIdx.x;
  if (idx >= 512 * KTOT) return;
  int o = idx / KTOT, k = idx - o * KTOT;
  int r = k >> 10, c = k & 1023;
  Apk[idx] = f2bf(W1[((size_t)o * CIN + c) * 9 + r]);
}

// ---------- prep: W2 [120][512] f32 -> W2p [128][512] bf16 ----------
__global__ void k_pack_w2(const float* __restrict__ W2, uint16_t* __restrict__ W2p) {
  int idx = blockIdx.x * 256 + threadIdx.x;
  int j = idx >> 9, o = idx & 511;
  W2p[idx] = (j < 120) ? f2bf(W2[j * 512 + o]) : (uint16_t)0;
}

// ---------- conv1: deep-pipelined implicit GEMM, 8 waves ----------
// BM=256(q) x BN=128(o) x BK=64, 8 waves (4Mx2N, per-wave 64x64), 3 LDS slots.
// Slot = A[256][64] (32KB) + B[128][64] (16KB) = 48KB; 3 slots = 144KB.
// K-order: t = cblock*9 + tap  (tap-inner => 9 tap re-reads of a slice are L2-hot).
// T2: byte ^= (row&7)<<4 swizzle (pre-swizzled global src, XOR'd ds_read cols).
// T3/T4: 2 phases/tile {8 ds_read, 3 stage, barrier, 16 MFMA}, counted vmcnt(6).
// T5: setprio around each MFMA cluster. 2 waves/SIMD for cross-wave overlap.
__global__ __launch_bounds__(512, 1) void k_conv1(
    const uint16_t* __restrict__ Xp, const uint16_t* __restrict__ Apk,
    const float* __restrict__ b1, uint16_t* __restrict__ x1) {
  __shared__ __align__(16) uint16_t lds[3 * 24576];   // 147456 B

  const int tid  = threadIdx.x;
  const int wid  = tid >> 6, lane = tid & 63;
  const int lrow = lane & 15, lq = lane >> 4;
  const int wm   = wid >> 1,  wn = wid & 1;           // 4M x 2N

  // grid decode: mt-major XCD chunking (384 = 8 XCDs * 48; blocks sharing an
  // A-panel (same mt, 4 nt) are consecutive => same XCD's L2)
  const int bid = blockIdx.x;
  const int g   = (bid & 7) * 48 + (bid >> 3);
  const int mt  = g >> 2, nt = g & 3;
  const int batch = mt / 6, qb = (mt - batch * 6) * 256;
  const int o0 = nt * 128;
  const uint16_t* Xb = Xp + (size_t)batch * QP * CIN;

  // fragment-read swizzled column offsets (elements); lds_byte = glob_byte ^ ((row&7)<<4)
  const int xorb    = (lrow & 7) << 4;
  const int col_el0 = ((lq * 16) ^ xorb) >> 1;   // kk=0
  const int col_el1 = col_el0 ^ 32;              // kk=1: toggle byte bit 6 (XOR)

  // staging: 512 threads, srow = tid>>3 (0..63), chunk ch = tid&7, pre-swizzled source col
  const int scol = ((tid & 7) ^ ((tid >> 3) & 7)) * 8;   // elements
  const int srow = tid >> 3;

  f32x4 acc[4][4] = {};

#define STAGE3(u, j0) do {                                                            \
    if ((u) < NTIL) {                                                                 \
      const int cb_  = (u) / 9;                                                       \
      const int tap_ = (u) - cb_ * 9;                                                 \
      const int off_ = (tap_ / 3) * QW + tap_ % 3;                                    \
      const int c0_  = cb_ << 6;                                                      \
      uint16_t* sl = lds + ((u) % 3) * 24576;                                         \
      _Pragma("unroll")                                                               \
      for (int jj = 0; jj < 3; ++jj) {                                                \
        const int j = (j0) + jj;                                                      \
        if (j < 4) {                                                                  \
          const int row = j * 64 + srow;                                              \
          gll16(Xb + (size_t)(qb + off_ + row) * CIN + c0_ + scol,                    \
                sl + j * 4096 + wid * 512);                                           \
        } else {                                                                      \
          const int row = (j - 4) * 64 + srow;                                        \
          gll16(Apk + (size_t)(o0 + row) * KTOT + (tap_ << 10) + c0_ + scol,          \
                sl + 16384 + (j - 4) * 4096 + wid * 512);                             \
        }                                                                             \
      }                                                                               \
    }                                                                                 \
  } while (0)

#define PHASE(kk, stj) do {                                                           \
    bf16x8 av[4], bv[4];                                                              \
    const int ce = (kk) ? col_el1 : col_el0;                                          \
    const uint16_t* As = lds + slot * 24576;                                          \
    const uint16_t* Bs = As + 16384;                                                  \
    _Pragma("unroll")                                                                 \
    for (int m = 0; m < 4; ++m)                                                       \
      av[m] = *(const bf16x8*)(As + (wm * 64 + m * 16 + lrow) * 64 + ce);             \
    _Pragma("unroll")                                                                 \
    for (int n = 0; n < 4; ++n)                                                       \
      bv[n] = *(const bf16x8*)(Bs + (wn * 64 + n * 16 + lrow) * 64 + ce);             \
    STAGE3(t + 2, stj);                                                               \
    asm volatile("s_barrier" ::: "memory");                                           \
    __builtin_amdgcn_sched_barrier(0);                                                \
    __builtin_amdgcn_s_setprio(1);                                                    \
    _Pragma("unroll")                                                                 \
    for (int m = 0; m < 4; ++m)                                                       \
      _Pragma("unroll")                                                               \
      for (int n = 0; n < 4; ++n)                                                     \
        acc[m][n] = __builtin_amdgcn_mfma_f32_16x16x32_bf16(                          \
            av[m], bv[n], acc[m][n], 0, 0, 0);                                        \
    __builtin_amdgcn_s_setprio(0);                                                    \
  } while (0)

  // prologue: stage tiles 0 and 1 (6 loads each)
  STAGE3(0, 0); STAGE3(0, 3);
  STAGE3(1, 0); STAGE3(1, 3);

  for (int t = 0; t < NTIL; ++t) {
    const int slot = t % 3;
    if (t == NTIL - 1) asm volatile("s_waitcnt vmcnt(0)" ::: "memory");
    else               asm volatile("s_waitcnt vmcnt(6)" ::: "memory");
    asm volatile("s_barrier" ::: "memory");
    __builtin_amdgcn_sched_barrier(0);
    PHASE(0, 0);
    PHASE(1, 3);
  }

  // epilogue: bias + ReLU6 -> x1 bf16
  const int qr = lq * 4;
#pragma unroll
  for (int n = 0; n < 4; ++n) {
    const int o = o0 + wn * 64 + n * 16 + lrow;
    const float bias = b1[o];
#pragma unroll
    for (int m = 0; m < 4; ++m) {
#pragma unroll
      for (int v = 0; v < 4; ++v) {
        const int q = qb + wm * 64 + m * 16 + qr + v;
        float x = acc[m][n][v] + bias;
        x = fminf(fmaxf(x, 0.f), 6.f);
        x1[((size_t)batch * QT + q) * CMID + o] = f2bf(x);
      }
    }
  }
#undef PHASE
#undef STAGE3
}

// ---------- conv2: out[b][h][w][j] = sum_o x1[q][o] * W2[j][o] + b2[j] ----------
__global__ __launch_bounds__(256, 2) void k_conv2(
    const uint16_t* __restrict__ x1, const uint16_t* __restrict__ W2p,
    const float* __restrict__ b2, float* __restrict__ out) {
  __shared__ __align__(16) uint16_t lA[128 * 64];
  __shared__ __align__(16) uint16_t lB[128 * 64];
  const int tid = threadIdx.x;
  const int wid = tid >> 6, lane = tid & 63;
  const int b = blockIdx.z, q0 = blockIdx.x * 128;
  const uint16_t* Ab = x1 + (size_t)b * QT * CMID;
  const int wm = wid >> 1, wn = wid & 1;
  const int lrow = lane & 15, lk = (lane >> 4) * 8;
  f32x4 acc[4][4] = {};

  for (int kt = 0; kt < 8; ++kt) {
    const int c0 = kt << 6;
#pragma unroll
    for (int i = 0; i < 4; ++i) {
      int wb = i * 256 + wid * 64;
      int chunk = wb + lane;
      int row = chunk >> 3, ch = chunk & 7;
      gll16(Ab + (size_t)(q0 + row) * CMID + c0 + ch * 8, lA + wb * 8);
      gll16(W2p + (size_t)row * CMID + c0 + ch * 8, lB + wb * 8);
    }
    __syncthreads();
#pragma unroll
    for (int kk = 0; kk < 2; ++kk) {
      bf16x8 av[4], bv[4];
#pragma unroll
      for (int mi = 0; mi < 4; ++mi)
        av[mi] = *(const bf16x8*)(lA + (wm * 64 + mi * 16 + lrow) * 64 + kk * 32 + lk);
#pragma unroll
      for (int ni = 0; ni < 4; ++ni)
        bv[ni] = *(const bf16x8*)(lB + (wn * 64 + ni * 16 + lrow) * 64 + kk * 32 + lk);
#pragma unroll
      for (int mi = 0; mi < 4; ++mi)
#pragma unroll
        for (int ni = 0; ni < 4; ++ni)
          acc[mi][ni] = __builtin_amdgcn_mfma_f32_16x16x32_bf16(av[mi], bv[ni], acc[mi][ni], 0, 0, 0);
    }
    __syncthreads();
  }

  const int qr = (lane >> 4) * 4;
#pragma unroll
  for (int ni = 0; ni < 4; ++ni) {
    int j = wn * 64 + ni * 16 + lrow;
    if (j < 120) {
      float bias = b2[j];
#pragma unroll
      for (int mi = 0; mi < 4; ++mi) {
#pragma unroll
        for (int v = 0; v < 4; ++v) {
          int q = q0 + wm * 64 + mi * 16 + qr + v;
          int h = q / QW, w = q - h * QW;
          if (h < 37 && w < 37) {
            out[((size_t)b * HW + h * 37 + w) * 120 + j] = acc[mi][ni][v] + bias;
          }
        }
      }
    }
  }
}

extern "C" void kernel_launch(void* const* d_in, const int* in_sizes, int n_in,
                              void* d_out, int out_size, void* d_ws, size_t ws_size,
                              hipStream_t stream) {
  const float* fmap = (const float*)d_in[0];
  const float* W1   = (const float*)d_in[1];
  const float* b1   = (const float*)d_in[2];
  const float* W2   = (const float*)d_in[3];
  const float* b2   = (const float*)d_in[4];
  float* out = (float*)d_out;

  uint8_t* ws = (uint8_t*)d_ws;
  const size_t XP_BYTES  = (size_t)16 * QP * CIN * 2;   // 52,953,088
  const size_t W1P_BYTES = (size_t)512 * KTOT * 2;      //  9,437,184
  const size_t W2P_BYTES = (size_t)128 * 512 * 2;       //    131,072
  uint16_t* Xp  = (uint16_t*)ws;
  uint16_t* Apk = (uint16_t*)(ws + XP_BYTES);
  uint16_t* W2p = (uint16_t*)(ws + XP_BYTES + W1P_BYTES);
  uint16_t* x1  = (uint16_t*)(ws + XP_BYTES + W1P_BYTES + W2P_BYTES);

  hipMemsetAsync(Xp, 0, XP_BYTES, stream);
  k_pad_transpose<<<dim3(43, 32, 16), dim3(32, 8), 0, stream>>>(fmap, Xp);
  k_pack_w1<<<dim3((512 * KTOT + 255) / 256), dim3(256), 0, stream>>>(W1, Apk);
  k_pack_w2<<<dim3(256), dim3(256), 0, stream>>>(W2, W2p);
  k_conv1<<<dim3(384), dim3(512), 0, stream>>>(Xp, Apk, b1, x1);
  k_conv2<<<dim3(12, 1, 16), dim3(256), 0, stream>>>(x1, W2p, b2, out);
}

// Round 6
// 263.346 us; speedup vs baseline: 1.4795x; 1.3095x over previous
//
#include <hip/hip_runtime.h>
#include <stdint.h>

#define HW   1369      // 37*37 output pixels
#define QW   39        // padded row width
#define QP   1616      // padded plane rows per (b) in Xp
#define QT   1536      // q rows in x1 (per batch)
#define CIN  1024
#define CMID 512
#define KTOT 9216      // 9 * 1024
#define NTIL 144       // K-tiles: 16 cblocks(64) * 9 taps, cblock-major tap-inner
#define SLOT 28672     // LDS slot stride in elements: A 192x64 + B 256x64 = 56KB

typedef float  f32x4  __attribute__((ext_vector_type(4)));
typedef __bf16 bf16x8 __attribute__((ext_vector_type(8)));

__device__ __forceinline__ uint16_t f2bf(float f) {
  uint32_t u = __float_as_uint(f);
  u += 0x7fffu + ((u >> 16) & 1u);
  return (uint16_t)(u >> 16);
}

// global -> LDS direct copy, 16B per lane. LDS dest = wave-uniform base + lane*16.
__device__ __forceinline__ void gll16(const void* g, void* l) {
  const __attribute__((address_space(1))) uint32_t* ga =
      (const __attribute__((address_space(1))) uint32_t*)(uintptr_t)g;
  __attribute__((address_space(3))) uint32_t* la =
      (__attribute__((address_space(3))) uint32_t*)(uint32_t)(uintptr_t)l;
  __builtin_amdgcn_global_load_lds(ga, la, 16, 0, 0);
}

// ---------- prep: fmap [b][c][h][w] f32 -> Xp [b][q][c] bf16 (padded, zeroed border) ----------
__global__ void k_pad_transpose(const float* __restrict__ fmap, uint16_t* __restrict__ Xp) {
  __shared__ float t[32][33];
  const int b = blockIdx.z;
  const int c0 = blockIdx.y * 32;
  const int p0 = blockIdx.x * 32;
  const int tx = threadIdx.x, ty = threadIdx.y;
  const float* src = fmap + ((size_t)b * CIN + c0) * HW + p0;
#pragma unroll
  for (int i = 0; i < 4; ++i) {
    int cc = ty + i * 8;
    t[cc][tx] = (p0 + tx < HW) ? src[(size_t)cc * HW + tx] : 0.f;
  }
  __syncthreads();
#pragma unroll
  for (int i = 0; i < 4; ++i) {
    int pl = ty + i * 8;
    int p = p0 + pl;
    if (p < HW) {
      int h = p / 37, w = p - h * 37;
      int q = (h + 1) * QW + (w + 1);
      Xp[((size_t)b * QP + q) * CIN + c0 + tx] = f2bf(t[tx][pl]);
    }
  }
}

// ---------- prep: W1 [o][c][3][3] f32 -> Apk [o][r*1024+c] bf16 ----------
__global__ void k_pack_w1(const float* __restrict__ W1, uint16_t* __restrict__ Apk) {
  int idx = blockIdx.x * 256 + threadIdx.x;
  if (idx >= 512 * KTOT) return;
  int o = idx / KTOT, k = idx - o * KTOT;
  int r = k >> 10, c = k & 1023;
  Apk[idx] = f2bf(W1[((size_t)o * CIN + c) * 9 + r]);
}

// ---------- prep: W2 [120][512] f32 -> W2p [128][512] bf16 ----------
__global__ void k_pack_w2(const float* __restrict__ W2, uint16_t* __restrict__ W2p) {
  int idx = blockIdx.x * 256 + threadIdx.x;
  int j = idx >> 9, o = idx & 511;
  W2p[idx] = (j < 120) ? f2bf(W2[j * 512 + o]) : (uint16_t)0;
}

// ---------- conv1: implicit GEMM, BM=192 x BN=256 x BK=64 ----------
// 8 waves (2M x 4N, wave tile 96x64), 2 LDS slots, grid = exactly 256 blocks.
// K-order: t = cblock*9 + tap (tap-inner => A rows L2-hot across 9 taps).
// T2 swizzle: lds_byte = glob_byte ^ ((row&7)<<4); pre-swizzled global src.
// T4: counted vmcnt(7) at tile top (one 7-load stage in flight).
// 2-slot hazard: stage(t+2) overwrites the slot tile t reads -> lgkmcnt(0)
// fence + barrier after ALL reads, before stage issue.
__global__ __launch_bounds__(512, 1) void k_conv1(
    const uint16_t* __restrict__ Xp, const uint16_t* __restrict__ Apk,
    const float* __restrict__ b1, uint16_t* __restrict__ x1) {
  __shared__ __align__(16) uint16_t lds[2 * SLOT];   // 114688 B

  const int tid  = threadIdx.x;
  const int wid  = tid >> 6, lane = tid & 63;
  const int lrow = lane & 15, lq = lane >> 4;
  const int wm   = wid >> 2,  wn = wid & 3;           // 2M x 4N

  // grid: 256 blocks = 8 XCDs x 32, mt-major within XCD (nt pair adjacent)
  const int bid = blockIdx.x;
  const int g   = (bid & 7) * 32 + (bid >> 3);
  const int mt  = g >> 1, nt = g & 1;
  const int batch = mt >> 3, qb = (mt & 7) * 192;
  const int o0 = nt * 256;
  const uint16_t* Xb = Xp + (size_t)batch * QP * CIN;

  // fragment-read swizzled column offsets (elements)
  const int xorb    = (lrow & 7) << 4;
  const int col_el0 = ((lq * 16) ^ xorb) >> 1;   // kk=0
  const int col_el1 = col_el0 ^ 32;              // kk=1 (toggle byte bit 6)

  // staging: srow = tid>>3 (0..63), pre-swizzled source column
  const int scol = ((tid & 7) ^ ((tid >> 3) & 7)) * 8;   // elements
  const int srow = tid >> 3;

  f32x4 acc[6][4] = {};

#define STAGE(u) do {                                                                 \
    if ((u) < NTIL) {                                                                 \
      const int cb_  = (u) / 9;                                                       \
      const int tap_ = (u) - cb_ * 9;                                                 \
      const int off_ = (tap_ / 3) * QW + tap_ % 3;                                    \
      const int c0_  = cb_ << 6;                                                      \
      uint16_t* sl = lds + ((u) & 1) * SLOT;                                          \
      _Pragma("unroll")                                                               \
      for (int j = 0; j < 3; ++j)                                                     \
        gll16(Xb + (size_t)(qb + off_ + j * 64 + srow) * CIN + c0_ + scol,            \
              sl + j * 4096 + wid * 512);                                             \
      _Pragma("unroll")                                                               \
      for (int j = 0; j < 4; ++j)                                                     \
        gll16(Apk + (size_t)(o0 + j * 64 + srow) * KTOT + (tap_ << 10) + c0_ + scol,  \
              sl + 12288 + j * 4096 + wid * 512);                                     \
    }                                                                                 \
  } while (0)

#define READF(kk) do {                                                                \
    const int ce = (kk) ? col_el1 : col_el0;                                          \
    _Pragma("unroll")                                                                 \
    for (int m = 0; m < 6; ++m)                                                       \
      av[m] = *(const bf16x8*)(As + (wm * 96 + m * 16 + lrow) * 64 + ce);             \
    _Pragma("unroll")                                                                 \
    for (int n = 0; n < 4; ++n)                                                       \
      bv[n] = *(const bf16x8*)(Bs + (wn * 64 + n * 16 + lrow) * 64 + ce);             \
  } while (0)

#define MFMA24 do {                                                                   \
    __builtin_amdgcn_s_setprio(1);                                                    \
    _Pragma("unroll")                                                                 \
    for (int m = 0; m < 6; ++m)                                                       \
      _Pragma("unroll")                                                               \
      for (int n = 0; n < 4; ++n)                                                     \
        acc[m][n] = __builtin_amdgcn_mfma_f32_16x16x32_bf16(                          \
            av[m], bv[n], acc[m][n], 0, 0, 0);                                        \
    __builtin_amdgcn_s_setprio(0);                                                    \
  } while (0)

  // prologue: stage tiles 0 and 1
  STAGE(0);
  STAGE(1);

  for (int t = 0; t < NTIL; ++t) {
    const uint16_t* As = lds + (t & 1) * SLOT;
    const uint16_t* Bs = As + 12288;
    if (t >= NTIL - 1) asm volatile("s_waitcnt vmcnt(0)" ::: "memory");
    else               asm volatile("s_waitcnt vmcnt(7)" ::: "memory");
    asm volatile("s_barrier" ::: "memory");             // B1: slot (t&1) filled
    __builtin_amdgcn_sched_barrier(0);
    bf16x8 av[6], bv[4];
    READF(0);
    MFMA24;
    READF(1);
    asm volatile("s_waitcnt lgkmcnt(0)" ::: "memory");  // all my slot reads complete
    __builtin_amdgcn_sched_barrier(0);
    asm volatile("s_barrier" ::: "memory");             // B2: ALL waves done reading
    __builtin_amdgcn_sched_barrier(0);
    STAGE(t + 2);                                       // safe: overwrites read-done slot
    MFMA24;
  }

  // epilogue: bias + ReLU6 -> x1 bf16
  const int qr = lq * 4;
#pragma unroll
  for (int n = 0; n < 4; ++n) {
    const int o = o0 + wn * 64 + n * 16 + lrow;
    const float bias = b1[o];
#pragma unroll
    for (int m = 0; m < 6; ++m) {
#pragma unroll
      for (int v = 0; v < 4; ++v) {
        const int q = qb + wm * 96 + m * 16 + qr + v;
        float x = acc[m][n][v] + bias;
        x = fminf(fmaxf(x, 0.f), 6.f);
        x1[((size_t)batch * QT + q) * CMID + o] = f2bf(x);
      }
    }
  }
#undef MFMA24
#undef READF
#undef STAGE
}

// ---------- conv2: out[b][h][w][j] = sum_o x1[q][o] * W2[j][o] + b2[j] ----------
__global__ __launch_bounds__(256, 2) void k_conv2(
    const uint16_t* __restrict__ x1, const uint16_t* __restrict__ W2p,
    const float* __restrict__ b2, float* __restrict__ out) {
  __shared__ __align__(16) uint16_t lA[128 * 64];
  __shared__ __align__(16) uint16_t lB[128 * 64];
  const int tid = threadIdx.x;
  const int wid = tid >> 6, lane = tid & 63;
  const int b = blockIdx.z, q0 = blockIdx.x * 128;
  const uint16_t* Ab = x1 + (size_t)b * QT * CMID;
  const int wm = wid >> 1, wn = wid & 1;
  const int lrow = lane & 15, lk = (lane >> 4) * 8;
  f32x4 acc[4][4] = {};

  for (int kt = 0; kt < 8; ++kt) {
    const int c0 = kt << 6;
#pragma unroll
    for (int i = 0; i < 4; ++i) {
      int wb = i * 256 + wid * 64;
      int chunk = wb + lane;
      int row = chunk >> 3, ch = chunk & 7;
      gll16(Ab + (size_t)(q0 + row) * CMID + c0 + ch * 8, lA + wb * 8);
      gll16(W2p + (size_t)row * CMID + c0 + ch * 8, lB + wb * 8);
    }
    __syncthreads();
#pragma unroll
    for (int kk = 0; kk < 2; ++kk) {
      bf16x8 av[4], bv[4];
#pragma unroll
      for (int mi = 0; mi < 4; ++mi)
        av[mi] = *(const bf16x8*)(lA + (wm * 64 + mi * 16 + lrow) * 64 + kk * 32 + lk);
#pragma unroll
      for (int ni = 0; ni < 4; ++ni)
        bv[ni] = *(const bf16x8*)(lB + (wn * 64 + ni * 16 + lrow) * 64 + kk * 32 + lk);
#pragma unroll
      for (int mi = 0; mi < 4; ++mi)
#pragma unroll
        for (int ni = 0; ni < 4; ++ni)
          acc[mi][ni] = __builtin_amdgcn_mfma_f32_16x16x32_bf16(av[mi], bv[ni], acc[mi][ni], 0, 0, 0);
    }
    __syncthreads();
  }

  const int qr = (lane >> 4) * 4;
#pragma unroll
  for (int ni = 0; ni < 4; ++ni) {
    int j = wn * 64 + ni * 16 + lrow;
    if (j < 120) {
      float bias = b2[j];
#pragma unroll
      for (int mi = 0; mi < 4; ++mi) {
#pragma unroll
        for (int v = 0; v < 4; ++v) {
          int q = q0 + wm * 64 + mi * 16 + qr + v;
          int h = q / QW, w = q - h * QW;
          if (h < 37 && w < 37) {
            out[((size_t)b * HW + h * 37 + w) * 120 + j] = acc[mi][ni][v] + bias;
          }
        }
      }
    }
  }
}

extern "C" void kernel_launch(void* const* d_in, const int* in_sizes, int n_in,
                              void* d_out, int out_size, void* d_ws, size_t ws_size,
                              hipStream_t stream) {
  const float* fmap = (const float*)d_in[0];
  const float* W1   = (const float*)d_in[1];
  const float* b1   = (const float*)d_in[2];
  const float* W2   = (const float*)d_in[3];
  const float* b2   = (const float*)d_in[4];
  float* out = (float*)d_out;

  uint8_t* ws = (uint8_t*)d_ws;
  const size_t XP_BYTES  = (size_t)16 * QP * CIN * 2;   // 52,953,088
  const size_t W1P_BYTES = (size_t)512 * KTOT * 2;      //  9,437,184
  const size_t W2P_BYTES = (size_t)128 * 512 * 2;       //    131,072
  uint16_t* Xp  = (uint16_t*)ws;
  uint16_t* Apk = (uint16_t*)(ws + XP_BYTES);
  uint16_t* W2p = (uint16_t*)(ws + XP_BYTES + W1P_BYTES);
  uint16_t* x1  = (uint16_t*)(ws + XP_BYTES + W1P_BYTES + W2P_BYTES);

  hipMemsetAsync(Xp, 0, XP_BYTES, stream);
  k_pad_transpose<<<dim3(43, 32, 16), dim3(32, 8), 0, stream>>>(fmap, Xp);
  k_pack_w1<<<dim3((512 * KTOT + 255) / 256), dim3(256), 0, stream>>>(W1, Apk);
  k_pack_w2<<<dim3(256), dim3(256), 0, stream>>>(W2, W2p);
  k_conv1<<<dim3(256), dim3(512), 0, stream>>>(Xp, Apk, b1, x1);
  k_conv2<<<dim3(12, 1, 16), dim3(256), 0, stream>>>(x1, W2p, b2, out);
}